// Round 1
// baseline (126.853 us; speedup 1.0000x reference)
//
#include <hip/hip_runtime.h>

// CombinedLoss = 0.7 * class-weighted Dice + 0.3 * Sobel-boundary BCE
// [B=8,C=4,H=512,W=512] fp32. Binary boundary BCE == 100 * mismatch-rate.
// Register-streaming design: one wave = one full 512-col row strip (8 cols/lane),
// R_=8 output rows/wave (halo re-read 1.25x vs 1.5x at R_=4), 5-slot register row
// window, depth-2 prefetch, shuffle halos. No LDS tiles, no mid-kernel barriers.
// 512 blocks = 2 blocks/CU -> single residency round.

#define H_ 512
#define W_ 512
#define NIMG 32
#define NPIXF 8388608.0f
#define R_ 8        // output rows per wave
#define NBLK 512    // 32 img * 64 segs / 4 waves-per-block

__device__ __forceinline__ float sigf(float x) {
    return __builtin_amdgcn_rcpf(1.f + __expf(-x));
}

__launch_bounds__(256, 2)
__global__ void fused_loss_kernel(const float* __restrict__ logits,
                                  const float* __restrict__ targets,
                                  float4* __restrict__ part) {
    const int tid  = threadIdx.x;
    const int wid  = tid >> 6, lane = tid & 63;
    const int bx   = blockIdx.x;
    const int img  = bx >> 4;                  // 16 blocks per image
    const int seg  = ((bx & 15) << 2) | wid;   // 64 segments per image
    const int y0   = seg << 3;                 // 8 rows per segment

    const float* Lp = logits  + (size_t)img * (H_ * W_) + (lane << 3);
    const float* Tp = targets + (size_t)img * (H_ * W_) + (lane << 3);

    float p[5][8], t[5][8];   // 5-slot row window, 8 cols/lane

    auto loadrow = [&](int gy, int s) {
        if ((unsigned)gy < (unsigned)H_) {
            const float4 va = *(const float4*)(Lp + gy * W_);
            const float4 vb = *(const float4*)(Lp + gy * W_ + 4);
            const float4 vc = *(const float4*)(Tp + gy * W_);
            const float4 vd = *(const float4*)(Tp + gy * W_ + 4);
            p[s][0] = sigf(va.x); p[s][1] = sigf(va.y);
            p[s][2] = sigf(va.z); p[s][3] = sigf(va.w);
            p[s][4] = sigf(vb.x); p[s][5] = sigf(vb.y);
            p[s][6] = sigf(vb.z); p[s][7] = sigf(vb.w);
            t[s][0] = vc.x; t[s][1] = vc.y; t[s][2] = vc.z; t[s][3] = vc.w;
            t[s][4] = vd.x; t[s][5] = vd.y; t[s][6] = vd.z; t[s][7] = vd.w;
        } else {
            #pragma unroll
            for (int k = 0; k < 8; ++k) { p[s][k] = 0.f; t[s][k] = 0.f; }
        }
    };

    loadrow(y0 - 1, 0);
    loadrow(y0,     1);
    loadrow(y0 + 1, 2);
    loadrow(y0 + 2, 3);

    float li = 0.f, lp = 0.f, lt = 0.f;
    int mi = 0;

    #pragma unroll
    for (int i = 0; i < R_; ++i) {
        if (i < R_ - 2) loadrow(y0 + 3 + i, (4 + i) % 5);   // depth-2 prefetch
        const int sA = i % 5, sB = (i + 1) % 5, sC = (i + 2) % 5;

        float Tc[8], Sc[8], Tt[8], St[8];
        #pragma unroll
        for (int k = 0; k < 8; ++k) {
            Tc[k] = (p[sA][k] + p[sC][k]) + 2.f * p[sB][k];
            Sc[k] = p[sC][k] - p[sA][k];
            Tt[k] = (t[sA][k] + t[sC][k]) + 2.f * t[sB][k];
            St[k] = t[sC][k] - t[sA][k];
        }
        // horizontal halo from neighbor lanes
        float TL = __shfl_up(Tc[7], 1, 64), TR = __shfl_down(Tc[0], 1, 64);
        float SL = __shfl_up(Sc[7], 1, 64), SR = __shfl_down(Sc[0], 1, 64);
        float UL = __shfl_up(Tt[7], 1, 64), UR = __shfl_down(Tt[0], 1, 64);
        float VL = __shfl_up(St[7], 1, 64), VR = __shfl_down(St[0], 1, 64);
        if (lane == 0)  { TL = 0.f; SL = 0.f; UL = 0.f; VL = 0.f; }
        if (lane == 63) { TR = 0.f; SR = 0.f; UR = 0.f; VR = 0.f; }

        #pragma unroll
        for (int k = 0; k < 8; ++k) {
            const float tl = (k == 0) ? TL : Tc[k - 1];
            const float tr = (k == 7) ? TR : Tc[k + 1];
            const float sl = (k == 0) ? SL : Sc[k - 1];
            const float sr = (k == 7) ? SR : Sc[k + 1];
            const float gx = tr - tl;
            const float gy = (sl + sr) + 2.f * Sc[k];
            const int pb = (gx * gx + gy * gy) > 0.25f;

            const float ul = (k == 0) ? UL : Tt[k - 1];
            const float ur = (k == 7) ? UR : Tt[k + 1];
            const float vl = (k == 0) ? VL : St[k - 1];
            const float vr = (k == 7) ? VR : St[k + 1];
            const float hx = ur - ul;
            const float hy = (vl + vr) + 2.f * St[k];
            const int tb = (hx * hx + hy * hy) > 0.25f;   // exact: integer-valued

            mi += pb ^ tb;
            const float pv = p[sB][k], tv = t[sB][k];
            lp += pv; lt += tv; li += pv * tv;
        }
    }
    float lm = (float)mi;

    #pragma unroll
    for (int off = 32; off > 0; off >>= 1) {
        li += __shfl_down(li, off, 64);
        lp += __shfl_down(lp, off, 64);
        lt += __shfl_down(lt, off, 64);
        lm += __shfl_down(lm, off, 64);
    }
    __shared__ float red[4][4];
    if (lane == 0) { red[wid][0] = li; red[wid][1] = lp; red[wid][2] = lt; red[wid][3] = lm; }
    __syncthreads();
    if (tid == 0) {
        float a = 0.f, b = 0.f, c = 0.f, d = 0.f;
        #pragma unroll
        for (int w = 0; w < 4; ++w) {
            a += red[w][0]; b += red[w][1]; c += red[w][2]; d += red[w][3];
        }
        part[bx] = make_float4(a, b, c, d);
    }
}

__global__ void finalize_kernel(const float4* __restrict__ part,
                                const float* __restrict__ cw,
                                float* __restrict__ out) {
    __shared__ float s_i[NIMG], s_p[NIMG], s_t[NIMG], s_m[NIMG];
    const int tid = threadIdx.x;           // 512 threads, one per block-partial
    float4 v = part[tid];
    float vi = v.x, vp = v.y, vt = v.z, vm = v.w;
    #pragma unroll
    for (int off = 8; off > 0; off >>= 1) {    // 16 partials per image, segmented
        vi += __shfl_down(vi, off, 16);
        vp += __shfl_down(vp, off, 16);
        vt += __shfl_down(vt, off, 16);
        vm += __shfl_down(vm, off, 16);
    }
    if ((tid & 15) == 0) {
        const int img = tid >> 4;
        s_i[img] = vi; s_p[img] = vp; s_t[img] = vt; s_m[img] = vm;
    }
    __syncthreads();
    if (tid == 0) {
        float mm = 0.f;
        for (int i = 0; i < NIMG; ++i) mm += s_m[i];
        float wsum = 0.f, dl = 0.f;
        for (int c = 0; c < 4; ++c) {
            float md = 0.f;
            for (int b = 0; b < 8; ++b) {
                const int id = b * 4 + c;
                md += (2.f * s_i[id] + 1.f) / (s_p[id] + s_t[id] + 1.f);
            }
            md *= 0.125f;
            dl += cw[c] * (1.f - md);
            wsum += cw[c];
        }
        out[0] = 0.7f * (dl / wsum) + 0.3f * (100.f * mm / NPIXF);
    }
}

extern "C" void kernel_launch(void* const* d_in, const int* in_sizes, int n_in,
                              void* d_out, int out_size, void* d_ws, size_t ws_size,
                              hipStream_t stream) {
    const float* logits  = (const float*)d_in[0];
    const float* targets = (const float*)d_in[1];
    const float* cw      = (const float*)d_in[2];
    float* out = (float*)d_out;
    float4* part = (float4*)d_ws;   // NBLK * 16 B = 8 KB

    fused_loss_kernel<<<NBLK, 256, 0, stream>>>(logits, targets, part);
    finalize_kernel<<<1, NBLK, 0, stream>>>(part, cw, out);
}